// Round 4
// baseline (1869.196 us; speedup 1.0000x reference)
//
#include <hip/hip_runtime.h>
#include <cstdint>

#define D 128
#define H 4
#define N_ENT 100000
#define N_EDGE 400000
#define R 32

#define SCAN_NB ((N_ENT + 511) / 512)  // 196 blocks of 512 elements

// ---------------------------------------------------------------------------
// CSR build: histogram -> hierarchical scan (3 small kernels) -> scatter.
// Round-3 lesson: the single-block scan was the #1 dispatch (238 us, one CU).
// ---------------------------------------------------------------------------
__global__ void k_hist(const int* __restrict__ head, int* __restrict__ deg) {
  const int e = blockIdx.x * 256 + threadIdx.x;
  if (e < N_EDGE) atomicAdd(&deg[head[e]], 1);
}

// block b sums deg[b*512 .. +512) -> bsum[b]
__global__ __launch_bounds__(256) void k_scan1(const int* __restrict__ deg,
                                               int* __restrict__ bsum) {
  const int t = threadIdx.x;
  const int i = blockIdx.x * 512 + t * 2;
  int v0 = (i < N_ENT) ? deg[i] : 0;
  int v1 = (i + 1 < N_ENT) ? deg[i + 1] : 0;
  int s = v0 + v1;
#pragma unroll
  for (int k = 1; k < 64; k <<= 1) s += __shfl_xor(s, k);
  __shared__ int ws[4];
  if ((t & 63) == 0) ws[t >> 6] = s;
  __syncthreads();
  if (t == 0) bsum[blockIdx.x] = ws[0] + ws[1] + ws[2] + ws[3];
}

// single block: exclusive scan of bsum[0..SCAN_NB) -> bbase; off[N_ENT]=total
__global__ __launch_bounds__(256) void k_scan2(const int* __restrict__ bsum,
                                               int* __restrict__ bbase,
                                               int* __restrict__ off) {
  __shared__ int sh[256];
  const int t = threadIdx.x;
  const int v = (t < SCAN_NB) ? bsum[t] : 0;
  sh[t] = v;
  __syncthreads();
  for (int d = 1; d < 256; d <<= 1) {
    const int u = (t >= d) ? sh[t - d] : 0;
    __syncthreads();
    sh[t] += u;
    __syncthreads();
  }
  if (t < SCAN_NB) bbase[t] = sh[t] - v;
  if (t == SCAN_NB - 1) off[N_ENT] = sh[t];
}

// block b: exclusive scan within its 512-chunk + bbase[b] -> off, cur
__global__ __launch_bounds__(256) void k_scan3(const int* __restrict__ deg,
                                               const int* __restrict__ bbase,
                                               int* __restrict__ off,
                                               int* __restrict__ cur) {
  __shared__ int sh[256];
  const int t = threadIdx.x;
  const int i = blockIdx.x * 512 + t * 2;
  const int v0 = (i < N_ENT) ? deg[i] : 0;
  const int v1 = (i + 1 < N_ENT) ? deg[i + 1] : 0;
  const int s = v0 + v1;
  sh[t] = s;
  __syncthreads();
  for (int d = 1; d < 256; d <<= 1) {
    const int u = (t >= d) ? sh[t - d] : 0;
    __syncthreads();
    sh[t] += u;
    __syncthreads();
  }
  const int ex = sh[t] - s + bbase[blockIdx.x];
  if (i < N_ENT) {
    off[i] = ex;
    cur[i] = ex;
  }
  if (i + 1 < N_ENT) {
    off[i + 1] = ex + v0;
    cur[i + 1] = ex + v0;
  }
}

__global__ void k_scatter(const int* __restrict__ head,
                          const int* __restrict__ tail,
                          const int* __restrict__ etype, int* __restrict__ cur,
                          int* __restrict__ tailP, int* __restrict__ etypeP) {
  const int e = blockIdx.x * 256 + threadIdx.x;
  if (e >= N_EDGE) return;
  const int hd = head[e];
  const int pos = atomicAdd(&cur[hd], 1);
  tailP[pos] = tail[e];
  etypeP[pos] = etype[e] - 1;
}

// ---------------------------------------------------------------------------
// K1: Q = entity_emb @ qTrans   (Q stored in d_out; consumed & overwritten
// row-by-row by k_attagg_all)
// ---------------------------------------------------------------------------
__global__ __launch_bounds__(512) void k_qproj(const float* __restrict__ ent,
                                               const float* __restrict__ qT,
                                               float* __restrict__ Q) {
  __shared__ float sT[D * D];
  __shared__ float rows[D * 128];
  const int t = threadIdx.x;
  const int n0 = blockIdx.x * 128;
#pragma unroll
  for (int s = 0; s < 8; ++s) {
    const int idx = (s * 512 + t) * 4;
    *(float4*)&sT[idx] = *(const float4*)&qT[idx];
  }
  {
    const int g = t & 3;
    const int n = t >> 2;
    const int node = n0 + n;
    if (node < N_ENT) {
      const float* src = ent + (size_t)node * D;
#pragma unroll
      for (int s = 0; s < 8; ++s) {
        const int i = s * 16 + g * 4;
        float4 v = *(const float4*)&src[i];
        rows[(i + 0) * 128 + n] = v.x;
        rows[(i + 1) * 128 + n] = v.y;
        rows[(i + 2) * 128 + n] = v.z;
        rows[(i + 3) * 128 + n] = v.w;
      }
    } else {
#pragma unroll
      for (int s = 0; s < 8; ++s) {
        const int i = s * 16 + g * 4;
        rows[(i + 0) * 128 + n] = 0.f;
        rows[(i + 1) * 128 + n] = 0.f;
        rows[(i + 2) * 128 + n] = 0.f;
        rows[(i + 3) * 128 + n] = 0.f;
      }
    }
  }
  __syncthreads();
  const int jj = t & 15;
  const int ee = t >> 4;
  float acc[4][8];
#pragma unroll
  for (int a = 0; a < 4; ++a)
#pragma unroll
    for (int b = 0; b < 8; ++b) acc[a][b] = 0.f;
#pragma unroll 4
  for (int i = 0; i < D; ++i) {
    float4 b0 = *(float4*)&sT[i * D + jj * 8];
    float4 b1 = *(float4*)&sT[i * D + jj * 8 + 4];
    float4 a0 = *(float4*)&rows[i * 128 + ee * 4];
    float bv[8] = {b0.x, b0.y, b0.z, b0.w, b1.x, b1.y, b1.z, b1.w};
    float av[4] = {a0.x, a0.y, a0.z, a0.w};
#pragma unroll
    for (int a = 0; a < 4; ++a)
#pragma unroll
      for (int b = 0; b < 8; ++b) acc[a][b] = fmaf(av[a], bv[b], acc[a][b]);
  }
#pragma unroll
  for (int a = 0; a < 4; ++a) {
    const int node = n0 + ee * 4 + a;
    if (node < N_ENT) {
      float4 o0 = {acc[a][0], acc[a][1], acc[a][2], acc[a][3]};
      float4 o1 = {acc[a][4], acc[a][5], acc[a][6], acc[a][7]};
      *(float4*)&Q[(size_t)node * D + jj * 8] = o0;
      *(float4*)&Q[(size_t)node * D + jj * 8 + 4] = o1;
    }
  }
}

// ---------------------------------------------------------------------------
// K2: ALL-HEADS fused per-node attention (merges round-3's 4 passes into 1;
// edge gather + Q-row read + LDS staging now happen once instead of 4x).
// One wave per node n, 16 nodes per 1024-thread block, full kT+vT in LDS
// (128 KB -> 1 block/CU, 16 waves/CU).
//   1. P_h[i] = sum_c kT[i,32h+c] * Q[n,32h+c]   (all 4 heads in registers)
//   2. edge loop (2 edges in flight via wave halves): nh = ent[tail]*wrel[ty];
//      logit_h = nh . P_h; el_h = exp(clip); agg_h += el_h*nh; ssum_h += el_h
//   3. agg_h /= (ssum_h + 1e-8)
//   4. kg[n,32h+c] = sum_d agg_h[d] * vT[d,32h+c]
// qkg = d_out: row n's Q read at start, kg written to row n at end.
// ---------------------------------------------------------------------------
__global__ __launch_bounds__(1024, 4) void k_attagg_all(
    const float* __restrict__ ent, const float* __restrict__ wrel,
    const float* __restrict__ kT, const float* __restrict__ vT, float* qkg,
    const int* __restrict__ off, const int* __restrict__ tailP,
    const int* __restrict__ etypeP) {
  __shared__ float sKT[D * D];  // sKT[j][i] = kT[i][j]  (transposed)
  __shared__ float sVT[D * D];  // sVT[d][c] = vT[d][c]  (row-major)
  const int t = threadIdx.x;
  {  // stage kT transposed: thread t -> i = t&127, jg = t>>7 (16 cols)
    const int i = t & 127;
    const int jg = t >> 7;
    const float* kr = kT + (size_t)i * D + jg * 16;
#pragma unroll
    for (int s = 0; s < 4; ++s) {
      float4 v = *(const float4*)&kr[s * 4];
      const int j = jg * 16 + s * 4;
      sKT[(j + 0) * D + i] = v.x;
      sKT[(j + 1) * D + i] = v.y;
      sKT[(j + 2) * D + i] = v.z;
      sKT[(j + 3) * D + i] = v.w;
    }
  }
  {  // stage vT row-major: thread t -> d = t>>3, c0 = (t&7)*16
    const int d = t >> 3;
    const int c0 = (t & 7) * 16;
    const float* vr = vT + (size_t)d * D + c0;
#pragma unroll
    for (int s = 0; s < 4; ++s)
      *(float4*)&sVT[d * D + c0 + s * 4] = *(const float4*)&vr[s * 4];
  }
  __syncthreads();

  const int wid = t >> 6;
  const int lane = t & 63;
  const int half = lane >> 5;
  const int l32 = lane & 31;
  const int n = blockIdx.x * 16 + wid;
  if (n >= N_ENT) return;

  // Q row: lane holds cols {lane, 64+lane}
  const float qv0 = qkg[(size_t)n * D + lane];
  const float qv1 = qkg[(size_t)n * D + 64 + lane];

  // 1. P_h (lane holds P_h[l32*4..+4), replicated across halves)
  float4 P0 = {0, 0, 0, 0}, P1 = {0, 0, 0, 0};
  float4 P2 = {0, 0, 0, 0}, P3 = {0, 0, 0, 0};
#pragma unroll
  for (int c = 0; c < 32; ++c) {
    const float q0 = __shfl(qv0, c);        // head0: cols 0..31
    const float q1 = __shfl(qv0, 32 + c);   // head1: cols 32..63
    const float q2 = __shfl(qv1, c);        // head2: cols 64..95
    const float q3 = __shfl(qv1, 32 + c);   // head3: cols 96..127
    const float4 k0 = *(const float4*)&sKT[(0 * 32 + c) * D + l32 * 4];
    const float4 k1 = *(const float4*)&sKT[(1 * 32 + c) * D + l32 * 4];
    const float4 k2 = *(const float4*)&sKT[(2 * 32 + c) * D + l32 * 4];
    const float4 k3 = *(const float4*)&sKT[(3 * 32 + c) * D + l32 * 4];
    P0.x = fmaf(q0, k0.x, P0.x); P0.y = fmaf(q0, k0.y, P0.y);
    P0.z = fmaf(q0, k0.z, P0.z); P0.w = fmaf(q0, k0.w, P0.w);
    P1.x = fmaf(q1, k1.x, P1.x); P1.y = fmaf(q1, k1.y, P1.y);
    P1.z = fmaf(q1, k1.z, P1.z); P1.w = fmaf(q1, k1.w, P1.w);
    P2.x = fmaf(q2, k2.x, P2.x); P2.y = fmaf(q2, k2.y, P2.y);
    P2.z = fmaf(q2, k2.z, P2.z); P2.w = fmaf(q2, k2.w, P2.w);
    P3.x = fmaf(q3, k3.x, P3.x); P3.y = fmaf(q3, k3.y, P3.y);
    P3.z = fmaf(q3, k3.z, P3.z); P3.w = fmaf(q3, k3.w, P3.w);
  }

  // 2. edge loop (half 0 / half 1 in flight)
  float4 a0 = {0, 0, 0, 0}, a1 = {0, 0, 0, 0};
  float4 a2 = {0, 0, 0, 0}, a3 = {0, 0, 0, 0};
  float s0 = 0.f, s1 = 0.f, s2 = 0.f, s3 = 0.f;
  const int eb = off[n];
  const int deg = off[n + 1] - eb;
  for (int b = 0; b < deg; b += 2) {
    const int idx = b + half;
    const bool val = idx < deg;
    const int e = eb + (val ? idx : 0);
    const int tl = tailP[e];
    const int ty = etypeP[e];
    const float4 x = *(const float4*)&ent[(size_t)tl * D + l32 * 4];
    const float4 r = *(const float4*)&wrel[(size_t)ty * D + l32 * 4];
    const float4 nh = {x.x * r.x, x.y * r.y, x.z * r.z, x.w * r.w};
    float d0 = nh.x * P0.x + nh.y * P0.y + nh.z * P0.z + nh.w * P0.w;
    float d1 = nh.x * P1.x + nh.y * P1.y + nh.z * P1.z + nh.w * P1.w;
    float d2 = nh.x * P2.x + nh.y * P2.y + nh.z * P2.z + nh.w * P2.w;
    float d3 = nh.x * P3.x + nh.y * P3.y + nh.z * P3.z + nh.w * P3.w;
#pragma unroll
    for (int k = 1; k < 32; k <<= 1) {
      d0 += __shfl_xor(d0, k);
      d1 += __shfl_xor(d1, k);
      d2 += __shfl_xor(d2, k);
      d3 += __shfl_xor(d3, k);
    }
    const float e0 = val ? expf(fminf(fmaxf(d0, -10.f), 10.f)) : 0.f;
    const float e1 = val ? expf(fminf(fmaxf(d1, -10.f), 10.f)) : 0.f;
    const float e2 = val ? expf(fminf(fmaxf(d2, -10.f), 10.f)) : 0.f;
    const float e3 = val ? expf(fminf(fmaxf(d3, -10.f), 10.f)) : 0.f;
    a0.x = fmaf(e0, nh.x, a0.x); a0.y = fmaf(e0, nh.y, a0.y);
    a0.z = fmaf(e0, nh.z, a0.z); a0.w = fmaf(e0, nh.w, a0.w);
    a1.x = fmaf(e1, nh.x, a1.x); a1.y = fmaf(e1, nh.y, a1.y);
    a1.z = fmaf(e1, nh.z, a1.z); a1.w = fmaf(e1, nh.w, a1.w);
    a2.x = fmaf(e2, nh.x, a2.x); a2.y = fmaf(e2, nh.y, a2.y);
    a2.z = fmaf(e2, nh.z, a2.z); a2.w = fmaf(e2, nh.w, a2.w);
    a3.x = fmaf(e3, nh.x, a3.x); a3.y = fmaf(e3, nh.y, a3.y);
    a3.z = fmaf(e3, nh.z, a3.z); a3.w = fmaf(e3, nh.w, a3.w);
    s0 += e0; s1 += e1; s2 += e2; s3 += e3;
  }
  // combine halves
  a0.x += __shfl_xor(a0.x, 32); a0.y += __shfl_xor(a0.y, 32);
  a0.z += __shfl_xor(a0.z, 32); a0.w += __shfl_xor(a0.w, 32);
  a1.x += __shfl_xor(a1.x, 32); a1.y += __shfl_xor(a1.y, 32);
  a1.z += __shfl_xor(a1.z, 32); a1.w += __shfl_xor(a1.w, 32);
  a2.x += __shfl_xor(a2.x, 32); a2.y += __shfl_xor(a2.y, 32);
  a2.z += __shfl_xor(a2.z, 32); a2.w += __shfl_xor(a2.w, 32);
  a3.x += __shfl_xor(a3.x, 32); a3.y += __shfl_xor(a3.y, 32);
  a3.z += __shfl_xor(a3.z, 32); a3.w += __shfl_xor(a3.w, 32);
  s0 += __shfl_xor(s0, 32); s1 += __shfl_xor(s1, 32);
  s2 += __shfl_xor(s2, 32); s3 += __shfl_xor(s3, 32);

  // 3. normalize
  const float i0 = 1.f / (s0 + 1e-8f);
  const float i1 = 1.f / (s1 + 1e-8f);
  const float i2 = 1.f / (s2 + 1e-8f);
  const float i3 = 1.f / (s3 + 1e-8f);
  a0.x *= i0; a0.y *= i0; a0.z *= i0; a0.w *= i0;
  a1.x *= i1; a1.y *= i1; a1.z *= i1; a1.w *= i1;
  a2.x *= i2; a2.y *= i2; a2.z *= i2; a2.w *= i2;
  a3.x *= i3; a3.y *= i3; a3.z *= i3; a3.w *= i3;

  // 4. project: col c = 32h + l32; halves split d in [half*64, +64)
  float c0 = 0.f, c1 = 0.f, c2 = 0.f, c3 = 0.f;
#pragma unroll
  for (int g = 0; g < 16; ++g) {
    const int d = half * 64 + g * 4;
    const int src = d >> 2;  // lane (post-combine both halves hold full agg)
    const float b0x = __shfl(a0.x, src), b0y = __shfl(a0.y, src);
    const float b0z = __shfl(a0.z, src), b0w = __shfl(a0.w, src);
    const float b1x = __shfl(a1.x, src), b1y = __shfl(a1.y, src);
    const float b1z = __shfl(a1.z, src), b1w = __shfl(a1.w, src);
    const float b2x = __shfl(a2.x, src), b2y = __shfl(a2.y, src);
    const float b2z = __shfl(a2.z, src), b2w = __shfl(a2.w, src);
    const float b3x = __shfl(a3.x, src), b3y = __shfl(a3.y, src);
    const float b3z = __shfl(a3.z, src), b3w = __shfl(a3.w, src);
    c0 = fmaf(b0x, sVT[(d + 0) * D + 0 * 32 + l32], c0);
    c0 = fmaf(b0y, sVT[(d + 1) * D + 0 * 32 + l32], c0);
    c0 = fmaf(b0z, sVT[(d + 2) * D + 0 * 32 + l32], c0);
    c0 = fmaf(b0w, sVT[(d + 3) * D + 0 * 32 + l32], c0);
    c1 = fmaf(b1x, sVT[(d + 0) * D + 1 * 32 + l32], c1);
    c1 = fmaf(b1y, sVT[(d + 1) * D + 1 * 32 + l32], c1);
    c1 = fmaf(b1z, sVT[(d + 2) * D + 1 * 32 + l32], c1);
    c1 = fmaf(b1w, sVT[(d + 3) * D + 1 * 32 + l32], c1);
    c2 = fmaf(b2x, sVT[(d + 0) * D + 2 * 32 + l32], c2);
    c2 = fmaf(b2y, sVT[(d + 1) * D + 2 * 32 + l32], c2);
    c2 = fmaf(b2z, sVT[(d + 2) * D + 2 * 32 + l32], c2);
    c2 = fmaf(b2w, sVT[(d + 3) * D + 2 * 32 + l32], c2);
    c3 = fmaf(b3x, sVT[(d + 0) * D + 3 * 32 + l32], c3);
    c3 = fmaf(b3y, sVT[(d + 1) * D + 3 * 32 + l32], c3);
    c3 = fmaf(b3z, sVT[(d + 2) * D + 3 * 32 + l32], c3);
    c3 = fmaf(b3w, sVT[(d + 3) * D + 3 * 32 + l32], c3);
  }
  c0 += __shfl_xor(c0, 32);
  c1 += __shfl_xor(c1, 32);
  c2 += __shfl_xor(c2, 32);
  c3 += __shfl_xor(c3, 32);
  // half0 writes heads 0,1; half1 writes heads 2,3 (values identical)
  if (half == 0) {
    qkg[(size_t)n * D + 0 * 32 + l32] = c0;
    qkg[(size_t)n * D + 1 * 32 + l32] = c1;
  } else {
    qkg[(size_t)n * D + 2 * 32 + l32] = c2;
    qkg[(size_t)n * D + 3 * 32 + l32] = c3;
  }
}

// ---------------------------------------------------------------------------
// K3: S[n,r] = sum_d kg[n,d]^2 * wrel[r,d]^2  (w(e) = S[head,ty]*S[tail,ty])
// ---------------------------------------------------------------------------
__global__ __launch_bounds__(256) void k_S(const float* __restrict__ kg,
                                           const float* __restrict__ wrel,
                                           float* __restrict__ S) {
  __shared__ float sB[D * 32];  // sB[d][r] = wrel[r][d]^2
  __shared__ float sA[D * 64];  // sA[d][n] = kg[n][d]^2
  const int t = threadIdx.x;
  const int n0 = blockIdx.x * 64;
  {
    const int r = t & 31;
    const int qg = t >> 5;  // 0..7
#pragma unroll
    for (int s = 0; s < 4; ++s) {
      const int d = qg * 16 + s * 4;
      float4 b = *(const float4*)&wrel[(size_t)r * D + d];
      sB[(d + 0) * 32 + r] = b.x * b.x;
      sB[(d + 1) * 32 + r] = b.y * b.y;
      sB[(d + 2) * 32 + r] = b.z * b.z;
      sB[(d + 3) * 32 + r] = b.w * b.w;
    }
  }
  {
    const int nn = t & 63;
    const int dg = t >> 6;
    const int node = n0 + nn;
#pragma unroll
    for (int s = 0; s < 8; ++s) {
      const int d = dg * 32 + s * 4;
      float4 a = {0, 0, 0, 0};
      if (node < N_ENT) a = *(const float4*)&kg[(size_t)node * D + d];
      sA[(d + 0) * 64 + nn] = a.x * a.x;
      sA[(d + 1) * 64 + nn] = a.y * a.y;
      sA[(d + 2) * 64 + nn] = a.z * a.z;
      sA[(d + 3) * 64 + nn] = a.w * a.w;
    }
  }
  __syncthreads();
  const int nn2 = t >> 2;
  const int rg = t & 3;
  float acc[8];
#pragma unroll
  for (int c = 0; c < 8; ++c) acc[c] = 0.f;
#pragma unroll 4
  for (int d = 0; d < D; ++d) {
    const float a = sA[d * 64 + nn2];
    float4 b0 = *(float4*)&sB[d * 32 + rg * 8];
    float4 b1 = *(float4*)&sB[d * 32 + rg * 8 + 4];
    acc[0] = fmaf(a, b0.x, acc[0]);
    acc[1] = fmaf(a, b0.y, acc[1]);
    acc[2] = fmaf(a, b0.z, acc[2]);
    acc[3] = fmaf(a, b0.w, acc[3]);
    acc[4] = fmaf(a, b1.x, acc[4]);
    acc[5] = fmaf(a, b1.y, acc[5]);
    acc[6] = fmaf(a, b1.z, acc[6]);
    acc[7] = fmaf(a, b1.w, acc[7]);
  }
  const int node = n0 + nn2;
  if (node < N_ENT) {
    float4 o0 = {acc[0], acc[1], acc[2], acc[3]};
    float4 o1 = {acc[4], acc[5], acc[6], acc[7]};
    *(float4*)&S[(size_t)node * 32 + rg * 8] = o0;
    *(float4*)&S[(size_t)node * 32 + rg * 8 + 4] = o1;
  }
}

// ---------------------------------------------------------------------------
// K4: per-node online softmax over w(e)=S[n,ty]*S[tail,ty] + weighted gather.
// One wave per node; no atomics. Writes the final output (overwrites d_out).
// ---------------------------------------------------------------------------
__global__ __launch_bounds__(256) void k_out2(
    const float* __restrict__ ent, const float* __restrict__ S,
    const int* __restrict__ off, const int* __restrict__ tailP,
    const int* __restrict__ etypeP, float* __restrict__ out) {
  const int t = threadIdx.x;
  const int wid = t >> 6;
  const int lane = t & 63;
  const int n = blockIdx.x * 4 + wid;
  if (n >= N_ENT) return;
  const int eb = off[n];
  const int deg = off[n + 1] - eb;
  float accx = 0.f, accy = 0.f;
  float m = 0.f, ssum = 0.f;
  for (int b = 0; b < deg; b += 64) {
    const int idx = b + lane;
    const bool val = idx < deg;
    const int e = eb + (val ? idx : 0);
    const int tl = tailP[e];
    const int ty = etypeP[e];
    float w = val ? S[(size_t)n * 32 + ty] * S[(size_t)tl * 32 + ty] : -1.f;
    float cm = w;
#pragma unroll
    for (int k = 1; k < 64; k <<= 1) cm = fmaxf(cm, __shfl_xor(cm, k));
    const float mnew = fmaxf(m, cm);
    const float scale = expf(m - mnew);
    const float el = val ? expf(w - mnew) : 0.f;
    float cs = el;
#pragma unroll
    for (int k = 1; k < 64; k <<= 1) cs += __shfl_xor(cs, k);
    ssum = ssum * scale + cs;
    accx *= scale;
    accy *= scale;
    const int cnt = (deg - b < 64) ? deg - b : 64;
    for (int j = 0; j < cnt; ++j) {
      const float sj = __shfl(el, j);
      const int tlj = __shfl(tl, j);
      const float2 x = *(const float2*)&ent[(size_t)tlj * D + lane * 2];
      accx = fmaf(sj, x.x, accx);
      accy = fmaf(sj, x.y, accy);
    }
    m = mnew;
  }
  const float inv = (deg > 0) ? 1.f / ssum : 0.f;
  float2 o = {accx * inv, accy * inv};
  *(float2*)&out[(size_t)n * D + lane * 2] = o;
}

// ---------------------------------------------------------------------------
// Workspace (~17.2 MB):
//   S      [N*32] fp32  = 12.8 MB
//   off    [N+1] int, cur [N] int, deg [N] int
//   bsum   [SCAN_NB] int, bbase [SCAN_NB] int
//   tailP  [E] int, etypeP [E] int
// d_out timeline: Q (k_qproj) -> kg (k_attagg_all, row-wise in place)
//                 -> final output (k_out2). Only memset: deg (0.4 MB).
// ---------------------------------------------------------------------------
extern "C" void kernel_launch(void* const* d_in, const int* in_sizes, int n_in,
                              void* d_out, int out_size, void* d_ws,
                              size_t ws_size, hipStream_t stream) {
  const float* ent = (const float*)d_in[0];
  const float* wrel = (const float*)d_in[3];
  const float* qT = (const float*)d_in[4];
  const float* kT = (const float*)d_in[5];
  const float* vT = (const float*)d_in[6];
  const int* eidx = (const int*)d_in[7];
  const int* etype = (const int*)d_in[8];
  const int* head = eidx;
  const int* tail = eidx + N_EDGE;

  float* S = (float*)d_ws;
  int* off = (int*)(S + (size_t)N_ENT * 32);
  int* cur = off + (N_ENT + 1);
  int* deg = cur + N_ENT;
  int* bsum = deg + N_ENT;
  int* bbase = bsum + SCAN_NB;
  int* tailP = bbase + SCAN_NB;
  int* etypeP = tailP + N_EDGE;
  float* qkg = (float*)d_out;

  hipMemsetAsync(deg, 0, N_ENT * sizeof(int), stream);
  k_hist<<<(N_EDGE + 255) / 256, 256, 0, stream>>>(head, deg);
  k_scan1<<<SCAN_NB, 256, 0, stream>>>(deg, bsum);
  k_scan2<<<1, 256, 0, stream>>>(bsum, bbase, off);
  k_scan3<<<SCAN_NB, 256, 0, stream>>>(deg, bbase, off, cur);
  k_scatter<<<(N_EDGE + 255) / 256, 256, 0, stream>>>(head, tail, etype, cur,
                                                      tailP, etypeP);
  k_qproj<<<(N_ENT + 127) / 128, 512, 0, stream>>>(ent, qT, qkg);
  k_attagg_all<<<(N_ENT + 15) / 16, 1024, 0, stream>>>(ent, wrel, kT, vT, qkg,
                                                       off, tailP, etypeP);
  k_S<<<(N_ENT + 63) / 64, 256, 0, stream>>>(qkg, wrel, S);
  k_out2<<<(N_ENT + 3) / 4, 256, 0, stream>>>(ent, S, off, tailP, etypeP,
                                              qkg);
}

// Round 5
// 560.982 us; speedup vs baseline: 3.3320x; 3.3320x over previous
//
#include <hip/hip_runtime.h>
#include <cstdint>

#define D 128
#define H 4
#define N_ENT 100000
#define N_EDGE 400000
#define R 32

#define SCAN_NB ((N_ENT + 511) / 512)  // 196 blocks of 512 elements

// ---------------------------------------------------------------------------
// CSR build: histogram -> hierarchical scan -> scatter (permuted tail/etype).
// (Round-3 lesson: single-block scan was 238 us; hierarchical is ~10 us.)
// ---------------------------------------------------------------------------
__global__ void k_hist(const int* __restrict__ head, int* __restrict__ deg) {
  const int e = blockIdx.x * 256 + threadIdx.x;
  if (e < N_EDGE) atomicAdd(&deg[head[e]], 1);
}

__global__ __launch_bounds__(256) void k_scan1(const int* __restrict__ deg,
                                               int* __restrict__ bsum) {
  const int t = threadIdx.x;
  const int i = blockIdx.x * 512 + t * 2;
  int v0 = (i < N_ENT) ? deg[i] : 0;
  int v1 = (i + 1 < N_ENT) ? deg[i + 1] : 0;
  int s = v0 + v1;
#pragma unroll
  for (int k = 1; k < 64; k <<= 1) s += __shfl_xor(s, k);
  __shared__ int ws[4];
  if ((t & 63) == 0) ws[t >> 6] = s;
  __syncthreads();
  if (t == 0) bsum[blockIdx.x] = ws[0] + ws[1] + ws[2] + ws[3];
}

__global__ __launch_bounds__(256) void k_scan2(const int* __restrict__ bsum,
                                               int* __restrict__ bbase,
                                               int* __restrict__ off) {
  __shared__ int sh[256];
  const int t = threadIdx.x;
  const int v = (t < SCAN_NB) ? bsum[t] : 0;
  sh[t] = v;
  __syncthreads();
  for (int d = 1; d < 256; d <<= 1) {
    const int u = (t >= d) ? sh[t - d] : 0;
    __syncthreads();
    sh[t] += u;
    __syncthreads();
  }
  if (t < SCAN_NB) bbase[t] = sh[t] - v;
  if (t == SCAN_NB - 1) off[N_ENT] = sh[t];
}

__global__ __launch_bounds__(256) void k_scan3(const int* __restrict__ deg,
                                               const int* __restrict__ bbase,
                                               int* __restrict__ off,
                                               int* __restrict__ cur) {
  __shared__ int sh[256];
  const int t = threadIdx.x;
  const int i = blockIdx.x * 512 + t * 2;
  const int v0 = (i < N_ENT) ? deg[i] : 0;
  const int v1 = (i + 1 < N_ENT) ? deg[i + 1] : 0;
  const int s = v0 + v1;
  sh[t] = s;
  __syncthreads();
  for (int d = 1; d < 256; d <<= 1) {
    const int u = (t >= d) ? sh[t - d] : 0;
    __syncthreads();
    sh[t] += u;
    __syncthreads();
  }
  const int ex = sh[t] - s + bbase[blockIdx.x];
  if (i < N_ENT) {
    off[i] = ex;
    cur[i] = ex;
  }
  if (i + 1 < N_ENT) {
    off[i + 1] = ex + v0;
    cur[i + 1] = ex + v0;
  }
}

__global__ void k_scatter(const int* __restrict__ head,
                          const int* __restrict__ tail,
                          const int* __restrict__ etype, int* __restrict__ cur,
                          int* __restrict__ tailP, int* __restrict__ etypeP) {
  const int e = blockIdx.x * 256 + threadIdx.x;
  if (e >= N_EDGE) return;
  const int hd = head[e];
  const int pos = atomicAdd(&cur[hd], 1);
  tailP[pos] = tail[e];
  etypeP[pos] = etype[e] - 1;
}

// ---------------------------------------------------------------------------
// kTt[j*128+i] = kT[i*128+j]  (one-time 64 KB transpose so the fused kernel's
// P-phase reads are coalesced)
// ---------------------------------------------------------------------------
__global__ __launch_bounds__(256) void k_tr(const float* __restrict__ in,
                                            float* __restrict__ out) {
  __shared__ float tile[32][33];
  const int bx = blockIdx.x & 3, by = blockIdx.x >> 2;
  const int c = threadIdx.x & 31;
  const int r0 = (threadIdx.x >> 5) * 4;
#pragma unroll
  for (int i = 0; i < 4; ++i)
    tile[r0 + i][c] = in[(by * 32 + r0 + i) * 128 + bx * 32 + c];
  __syncthreads();
#pragma unroll
  for (int i = 0; i < 4; ++i)
    out[(bx * 32 + r0 + i) * 128 + by * 32 + c] = tile[c][r0 + i];
}

// ---------------------------------------------------------------------------
// K1: Q = entity_emb @ qTrans   (Q in d_out; consumed & overwritten by k_fused)
// ---------------------------------------------------------------------------
__global__ __launch_bounds__(512) void k_qproj(const float* __restrict__ ent,
                                               const float* __restrict__ qT,
                                               float* __restrict__ Q) {
  __shared__ float sT[D * D];
  __shared__ float rows[D * 128];
  const int t = threadIdx.x;
  const int n0 = blockIdx.x * 128;
#pragma unroll
  for (int s = 0; s < 8; ++s) {
    const int idx = (s * 512 + t) * 4;
    *(float4*)&sT[idx] = *(const float4*)&qT[idx];
  }
  {
    const int g = t & 3;
    const int n = t >> 2;
    const int node = n0 + n;
    if (node < N_ENT) {
      const float* src = ent + (size_t)node * D;
#pragma unroll
      for (int s = 0; s < 8; ++s) {
        const int i = s * 16 + g * 4;
        float4 v = *(const float4*)&src[i];
        rows[(i + 0) * 128 + n] = v.x;
        rows[(i + 1) * 128 + n] = v.y;
        rows[(i + 2) * 128 + n] = v.z;
        rows[(i + 3) * 128 + n] = v.w;
      }
    } else {
#pragma unroll
      for (int s = 0; s < 8; ++s) {
        const int i = s * 16 + g * 4;
        rows[(i + 0) * 128 + n] = 0.f;
        rows[(i + 1) * 128 + n] = 0.f;
        rows[(i + 2) * 128 + n] = 0.f;
        rows[(i + 3) * 128 + n] = 0.f;
      }
    }
  }
  __syncthreads();
  const int jj = t & 15;
  const int ee = t >> 4;
  float acc[4][8];
#pragma unroll
  for (int a = 0; a < 4; ++a)
#pragma unroll
    for (int b = 0; b < 8; ++b) acc[a][b] = 0.f;
#pragma unroll 4
  for (int i = 0; i < D; ++i) {
    float4 b0 = *(float4*)&sT[i * D + jj * 8];
    float4 b1 = *(float4*)&sT[i * D + jj * 8 + 4];
    float4 a0 = *(float4*)&rows[i * 128 + ee * 4];
    float bv[8] = {b0.x, b0.y, b0.z, b0.w, b1.x, b1.y, b1.z, b1.w};
    float av[4] = {a0.x, a0.y, a0.z, a0.w};
#pragma unroll
    for (int a = 0; a < 4; ++a)
#pragma unroll
      for (int b = 0; b < 8; ++b) acc[a][b] = fmaf(av[a], bv[b], acc[a][b]);
  }
#pragma unroll
  for (int a = 0; a < 4; ++a) {
    const int node = n0 + ee * 4 + a;
    if (node < N_ENT) {
      float4 o0 = {acc[a][0], acc[a][1], acc[a][2], acc[a][3]};
      float4 o1 = {acc[a][4], acc[a][5], acc[a][6], acc[a][7]};
      *(float4*)&Q[(size_t)node * D + jj * 8] = o0;
      *(float4*)&Q[(size_t)node * D + jj * 8 + 4] = o1;
    }
  }
}

// ---------------------------------------------------------------------------
// K2: fused all-heads attention, spill-proof restructure of round 4.
// 256 threads, 8 nodes/block (one node per 32-lane half-wave), 36 KB LDS.
// Round-4 lesson: 6 GB of scratch spill traffic (WRITE 3.9 GB vs 51 MB of
// real writes) from the register-fat single-phase version. Here each phase
// keeps <= ~70 VGPRs live.
//   P0: Q rows (8x128) -> sQ
//   P1: block-cooperative P[k,h,i] = sum_c kTt[32h+c,i]*sQ[k,32h+c] -> sP
//       (kTt element loaded once per block, 8-way node reuse)
//   P2: per-half-wave edge loop: nh=ent[tail]*wrel[ty]; logit_h=nh.P_h;
//       agg_h += exp(clip)*nh; normalized agg -> sAgg
//   P3: block-cooperative kg[n,c] = sum_d sAgg[k,c>>5,d]*vT[d,c] -> qkg row
// N_ENT = 100000 = 12500 * 8: no remainder guards needed.
// ---------------------------------------------------------------------------
__global__ __launch_bounds__(256, 4) void k_fused(
    const float* __restrict__ ent, const float* __restrict__ wrel,
    const float* __restrict__ kTt, const float* __restrict__ vT, float* qkg,
    const int* __restrict__ off, const int* __restrict__ tailP,
    const int* __restrict__ etypeP) {
  __shared__ float sQ[8 * 128];   //  4 KB
  __shared__ float sP[8 * 512];   // 16 KB
  __shared__ float sAgg[8 * 512]; // 16 KB
  const int t = threadIdx.x;
  const int base = blockIdx.x * 8;

  // P0: stage Q rows
  {
    const int k = t >> 5;
    const int c4 = (t & 31) * 4;
    *(float4*)&sQ[k * 128 + c4] =
        *(const float4*)&qkg[(size_t)(base + k) * D + c4];
  }
  __syncthreads();

  // P1: cooperative P-compute. thread t: i = t&127, sub = t>>7 (heads 2sub..)
  {
    const int i = t & 127;
    const int sub = t >> 7;
    float pp[2][8];
#pragma unroll
    for (int hh = 0; hh < 2; ++hh)
#pragma unroll
      for (int k = 0; k < 8; ++k) pp[hh][k] = 0.f;
#pragma unroll
    for (int hh = 0; hh < 2; ++hh) {
      const int h = sub * 2 + hh;
      for (int c = 0; c < 32; ++c) {
        const float kv = kTt[(h * 32 + c) * 128 + i];
#pragma unroll
        for (int k = 0; k < 8; ++k)
          pp[hh][k] = fmaf(kv, sQ[k * 128 + h * 32 + c], pp[hh][k]);
      }
    }
#pragma unroll
    for (int hh = 0; hh < 2; ++hh)
#pragma unroll
      for (int k = 0; k < 8; ++k)
        sP[k * 512 + (sub * 2 + hh) * 128 + i] = pp[hh][k];
  }
  __syncthreads();

  // P2: edge loop. half-wave owns one node.
  {
    const int wid = t >> 6;
    const int half = (t >> 5) & 1;
    const int l32 = t & 31;
    const int k = wid * 2 + half;
    const int n = base + k;
    const float4 P0 = *(const float4*)&sP[k * 512 + 0 * 128 + l32 * 4];
    const float4 P1 = *(const float4*)&sP[k * 512 + 1 * 128 + l32 * 4];
    const float4 P2 = *(const float4*)&sP[k * 512 + 2 * 128 + l32 * 4];
    const float4 P3 = *(const float4*)&sP[k * 512 + 3 * 128 + l32 * 4];
    float4 a0 = {0, 0, 0, 0}, a1 = {0, 0, 0, 0};
    float4 a2 = {0, 0, 0, 0}, a3 = {0, 0, 0, 0};
    float s0 = 0.f, s1 = 0.f, s2 = 0.f, s3 = 0.f;
    const int eb = off[n];
    const int deg = off[n + 1] - eb;
    for (int idx = 0; idx < deg; ++idx) {
      const int e = eb + idx;
      const int tl = tailP[e];
      const int ty = etypeP[e];
      const float4 x = *(const float4*)&ent[(size_t)tl * D + l32 * 4];
      const float4 r = *(const float4*)&wrel[(size_t)ty * D + l32 * 4];
      const float4 nh = {x.x * r.x, x.y * r.y, x.z * r.z, x.w * r.w};
      float d0 = nh.x * P0.x + nh.y * P0.y + nh.z * P0.z + nh.w * P0.w;
      float d1 = nh.x * P1.x + nh.y * P1.y + nh.z * P1.z + nh.w * P1.w;
      float d2 = nh.x * P2.x + nh.y * P2.y + nh.z * P2.z + nh.w * P2.w;
      float d3 = nh.x * P3.x + nh.y * P3.y + nh.z * P3.z + nh.w * P3.w;
#pragma unroll
      for (int s = 1; s < 32; s <<= 1) {
        d0 += __shfl_xor(d0, s);
        d1 += __shfl_xor(d1, s);
        d2 += __shfl_xor(d2, s);
        d3 += __shfl_xor(d3, s);
      }
      const float e0 = expf(fminf(fmaxf(d0, -10.f), 10.f));
      const float e1 = expf(fminf(fmaxf(d1, -10.f), 10.f));
      const float e2 = expf(fminf(fmaxf(d2, -10.f), 10.f));
      const float e3 = expf(fminf(fmaxf(d3, -10.f), 10.f));
      a0.x = fmaf(e0, nh.x, a0.x); a0.y = fmaf(e0, nh.y, a0.y);
      a0.z = fmaf(e0, nh.z, a0.z); a0.w = fmaf(e0, nh.w, a0.w);
      a1.x = fmaf(e1, nh.x, a1.x); a1.y = fmaf(e1, nh.y, a1.y);
      a1.z = fmaf(e1, nh.z, a1.z); a1.w = fmaf(e1, nh.w, a1.w);
      a2.x = fmaf(e2, nh.x, a2.x); a2.y = fmaf(e2, nh.y, a2.y);
      a2.z = fmaf(e2, nh.z, a2.z); a2.w = fmaf(e2, nh.w, a2.w);
      a3.x = fmaf(e3, nh.x, a3.x); a3.y = fmaf(e3, nh.y, a3.y);
      a3.z = fmaf(e3, nh.z, a3.z); a3.w = fmaf(e3, nh.w, a3.w);
      s0 += e0; s1 += e1; s2 += e2; s3 += e3;
    }
    const float i0 = 1.f / (s0 + 1e-8f);
    const float i1 = 1.f / (s1 + 1e-8f);
    const float i2 = 1.f / (s2 + 1e-8f);
    const float i3 = 1.f / (s3 + 1e-8f);
    float4 o0 = {a0.x * i0, a0.y * i0, a0.z * i0, a0.w * i0};
    float4 o1 = {a1.x * i1, a1.y * i1, a1.z * i1, a1.w * i1};
    float4 o2 = {a2.x * i2, a2.y * i2, a2.z * i2, a2.w * i2};
    float4 o3 = {a3.x * i3, a3.y * i3, a3.z * i3, a3.w * i3};
    *(float4*)&sAgg[k * 512 + 0 * 128 + l32 * 4] = o0;
    *(float4*)&sAgg[k * 512 + 1 * 128 + l32 * 4] = o1;
    *(float4*)&sAgg[k * 512 + 2 * 128 + l32 * 4] = o2;
    *(float4*)&sAgg[k * 512 + 3 * 128 + l32 * 4] = o3;
  }
  __syncthreads();

  // P3: cooperative vT projection. thread t: col c, 4 nodes per group.
  {
    const int c = t & 127;
    const int g4 = (t >> 7) * 4;
    const int h = c >> 5;
    float acc0 = 0.f, acc1 = 0.f, acc2 = 0.f, acc3 = 0.f;
    const float* agg0 = &sAgg[(g4 + 0) * 512 + h * 128];
    const float* agg1 = &sAgg[(g4 + 1) * 512 + h * 128];
    const float* agg2 = &sAgg[(g4 + 2) * 512 + h * 128];
    const float* agg3 = &sAgg[(g4 + 3) * 512 + h * 128];
#pragma unroll 4
    for (int d = 0; d < 128; ++d) {
      const float v = vT[d * 128 + c];
      acc0 = fmaf(agg0[d], v, acc0);
      acc1 = fmaf(agg1[d], v, acc1);
      acc2 = fmaf(agg2[d], v, acc2);
      acc3 = fmaf(agg3[d], v, acc3);
    }
    qkg[(size_t)(base + g4 + 0) * D + c] = acc0;
    qkg[(size_t)(base + g4 + 1) * D + c] = acc1;
    qkg[(size_t)(base + g4 + 2) * D + c] = acc2;
    qkg[(size_t)(base + g4 + 3) * D + c] = acc3;
  }
}

// ---------------------------------------------------------------------------
// K3: S[n,r] = sum_d kg[n,d]^2 * wrel[r,d]^2  (w(e) = S[head,ty]*S[tail,ty])
// ---------------------------------------------------------------------------
__global__ __launch_bounds__(256) void k_S(const float* __restrict__ kg,
                                           const float* __restrict__ wrel,
                                           float* __restrict__ S) {
  __shared__ float sB[D * 32];
  __shared__ float sA[D * 64];
  const int t = threadIdx.x;
  const int n0 = blockIdx.x * 64;
  {
    const int r = t & 31;
    const int qg = t >> 5;
#pragma unroll
    for (int s = 0; s < 4; ++s) {
      const int d = qg * 16 + s * 4;
      float4 b = *(const float4*)&wrel[(size_t)r * D + d];
      sB[(d + 0) * 32 + r] = b.x * b.x;
      sB[(d + 1) * 32 + r] = b.y * b.y;
      sB[(d + 2) * 32 + r] = b.z * b.z;
      sB[(d + 3) * 32 + r] = b.w * b.w;
    }
  }
  {
    const int nn = t & 63;
    const int dg = t >> 6;
    const int node = n0 + nn;
#pragma unroll
    for (int s = 0; s < 8; ++s) {
      const int d = dg * 32 + s * 4;
      float4 a = {0, 0, 0, 0};
      if (node < N_ENT) a = *(const float4*)&kg[(size_t)node * D + d];
      sA[(d + 0) * 64 + nn] = a.x * a.x;
      sA[(d + 1) * 64 + nn] = a.y * a.y;
      sA[(d + 2) * 64 + nn] = a.z * a.z;
      sA[(d + 3) * 64 + nn] = a.w * a.w;
    }
  }
  __syncthreads();
  const int nn2 = t >> 2;
  const int rg = t & 3;
  float acc[8];
#pragma unroll
  for (int c = 0; c < 8; ++c) acc[c] = 0.f;
#pragma unroll 4
  for (int d = 0; d < D; ++d) {
    const float a = sA[d * 64 + nn2];
    float4 b0 = *(float4*)&sB[d * 32 + rg * 8];
    float4 b1 = *(float4*)&sB[d * 32 + rg * 8 + 4];
    acc[0] = fmaf(a, b0.x, acc[0]);
    acc[1] = fmaf(a, b0.y, acc[1]);
    acc[2] = fmaf(a, b0.z, acc[2]);
    acc[3] = fmaf(a, b0.w, acc[3]);
    acc[4] = fmaf(a, b1.x, acc[4]);
    acc[5] = fmaf(a, b1.y, acc[5]);
    acc[6] = fmaf(a, b1.z, acc[6]);
    acc[7] = fmaf(a, b1.w, acc[7]);
  }
  const int node = n0 + nn2;
  if (node < N_ENT) {
    float4 o0 = {acc[0], acc[1], acc[2], acc[3]};
    float4 o1 = {acc[4], acc[5], acc[6], acc[7]};
    *(float4*)&S[(size_t)node * 32 + rg * 8] = o0;
    *(float4*)&S[(size_t)node * 32 + rg * 8 + 4] = o1;
  }
}

// ---------------------------------------------------------------------------
// K4: per-node online softmax over w(e)=S[n,ty]*S[tail,ty] + weighted gather.
// ---------------------------------------------------------------------------
__global__ __launch_bounds__(256) void k_out2(
    const float* __restrict__ ent, const float* __restrict__ S,
    const int* __restrict__ off, const int* __restrict__ tailP,
    const int* __restrict__ etypeP, float* __restrict__ out) {
  const int t = threadIdx.x;
  const int wid = t >> 6;
  const int lane = t & 63;
  const int n = blockIdx.x * 4 + wid;
  if (n >= N_ENT) return;
  const int eb = off[n];
  const int deg = off[n + 1] - eb;
  float accx = 0.f, accy = 0.f;
  float m = 0.f, ssum = 0.f;
  for (int b = 0; b < deg; b += 64) {
    const int idx = b + lane;
    const bool val = idx < deg;
    const int e = eb + (val ? idx : 0);
    const int tl = tailP[e];
    const int ty = etypeP[e];
    float w = val ? S[(size_t)n * 32 + ty] * S[(size_t)tl * 32 + ty] : -1.f;
    float cm = w;
#pragma unroll
    for (int k = 1; k < 64; k <<= 1) cm = fmaxf(cm, __shfl_xor(cm, k));
    const float mnew = fmaxf(m, cm);
    const float scale = expf(m - mnew);
    const float el = val ? expf(w - mnew) : 0.f;
    float cs = el;
#pragma unroll
    for (int k = 1; k < 64; k <<= 1) cs += __shfl_xor(cs, k);
    ssum = ssum * scale + cs;
    accx *= scale;
    accy *= scale;
    const int cnt = (deg - b < 64) ? deg - b : 64;
    for (int j = 0; j < cnt; ++j) {
      const float sj = __shfl(el, j);
      const int tlj = __shfl(tl, j);
      const float2 x = *(const float2*)&ent[(size_t)tlj * D + lane * 2];
      accx = fmaf(sj, x.x, accx);
      accy = fmaf(sj, x.y, accy);
    }
    m = mnew;
  }
  const float inv = (deg > 0) ? 1.f / ssum : 0.f;
  float2 o = {accx * inv, accy * inv};
  *(float2*)&out[(size_t)n * D + lane * 2] = o;
}

// ---------------------------------------------------------------------------
// Workspace (~17.4 MB):
//   S [N*32] fp32; off[N+1], cur[N], deg[N], bsum/bbase[SCAN_NB] int;
//   tailP/etypeP [E] int; kTt [128*128] fp32.
// d_out timeline: Q (k_qproj) -> kg (k_fused, in place) -> output (k_out2).
// ---------------------------------------------------------------------------
extern "C" void kernel_launch(void* const* d_in, const int* in_sizes, int n_in,
                              void* d_out, int out_size, void* d_ws,
                              size_t ws_size, hipStream_t stream) {
  const float* ent = (const float*)d_in[0];
  const float* wrel = (const float*)d_in[3];
  const float* qT = (const float*)d_in[4];
  const float* kT = (const float*)d_in[5];
  const float* vT = (const float*)d_in[6];
  const int* eidx = (const int*)d_in[7];
  const int* etype = (const int*)d_in[8];
  const int* head = eidx;
  const int* tail = eidx + N_EDGE;

  float* S = (float*)d_ws;
  int* off = (int*)(S + (size_t)N_ENT * 32);
  int* cur = off + (N_ENT + 1);
  int* deg = cur + N_ENT;
  int* bsum = deg + N_ENT;
  int* bbase = bsum + SCAN_NB;
  int* tailP = bbase + SCAN_NB;
  int* etypeP = tailP + N_EDGE;
  float* kTt = (float*)(etypeP + N_EDGE);
  float* qkg = (float*)d_out;

  hipMemsetAsync(deg, 0, N_ENT * sizeof(int), stream);
  k_hist<<<(N_EDGE + 255) / 256, 256, 0, stream>>>(head, deg);
  k_scan1<<<SCAN_NB, 256, 0, stream>>>(deg, bsum);
  k_scan2<<<1, 256, 0, stream>>>(bsum, bbase, off);
  k_scan3<<<SCAN_NB, 256, 0, stream>>>(deg, bbase, off, cur);
  k_scatter<<<(N_EDGE + 255) / 256, 256, 0, stream>>>(head, tail, etype, cur,
                                                      tailP, etypeP);
  k_tr<<<16, 256, 0, stream>>>(kT, kTt);
  k_qproj<<<(N_ENT + 127) / 128, 512, 0, stream>>>(ent, qT, qkg);
  k_fused<<<N_ENT / 8, 256, 0, stream>>>(ent, wrel, kTt, vT, qkg, off, tailP,
                                         etypeP);
  k_S<<<(N_ENT + 63) / 64, 256, 0, stream>>>(qkg, wrel, S);
  k_out2<<<(N_ENT + 3) / 4, 256, 0, stream>>>(ent, S, off, tailP, etypeP,
                                              qkg);
}